// Round 6
// baseline (159.523 us; speedup 1.0000x reference)
//
#include <hip/hip_runtime.h>
#include <stdint.h>

// ModulatedConv (StyleGAN2 up-conv): B=8, Cin=Cout=512, K=3, 32x32 -> 64x64, fp32 I/O.
// Factorized pipeline (style folded into X, demod into GEMM epilogue):
//   C[b,tap,o,hw] = dc[b,o] * sum_i (gain*w)[tap*512+o,i] * ((s[b,i]+1)*x[b,i,hw])
//   K1 k_prep:  blocks 0..511  = dc[b][o] (16 KB) + SHARED W' = gain*w bf16 [4608][512]
//               (4.7 MB, batch-independent!); blocks 512..1023 = XS[b][hw][i] bf16
//               (style-premultiplied transpose, 8.39 MB)
//   K2 k_gemm:  per batch GEMM M=4608,N=1024,K=512, A shared across batches (L2/L3-
//               resident). 192x256 tile, BK=64, 4-phase counted-vmcnt(7) schedule
//               (R2 structure, best measured 50.9us), dc multiply in epilogue.
//   K3 k_fir:   unchanged: parity scatter + separable 4x4 FIR per (b,o), 512 thr.

#define DI __device__ __forceinline__

typedef __bf16 bf16x8 __attribute__((ext_vector_type(8)));
typedef float f32x4 __attribute__((ext_vector_type(4)));

DI float bf2f(ushort u) { union { uint32_t i; float f; } v; v.i = ((uint32_t)u) << 16; return v.f; }
DI ushort f2bf(float f) {
  union { float f; uint32_t i; } v; v.f = f;
  uint32_t x = v.i;
  return (ushort)((x + 0x7FFFu + ((x >> 16) & 1u)) >> 16);  // RNE
}

#define GAIN (1.0f / 1536.0f)  // 1/sqrt(512*512*9)

// ---------------- K1: dcoef + shared-W' prep (0..511) | styled x-transpose (512..1023) --
__global__ __launch_bounds__(256) void k_prep(const float* __restrict__ w,
                                              const float* __restrict__ styles,
                                              const float* __restrict__ x,
                                              ushort* __restrict__ Wp,
                                              float* __restrict__ dcg,
                                              ushort* __restrict__ xs) {
  __shared__ union {
    struct { float ss[4096]; float wred[4][8]; } wp;
    float tl[32][257];
  } sm;
  __shared__ float sst[32];
  const int t = threadIdx.x;
  if (blockIdx.x < 512) {
    // ---- block per o. Thread t owns i = 2t, 2t+1. ----
    const int o = blockIdx.x;
#pragma unroll
    for (int j = 0; j < 4; j++) {
      const int idx = (t + j * 256) * 4;
      *(float4*)&sm.wp.ss[idx] = *(const float4*)&styles[idx];
    }
    float wreg[18];
    const float* wp_ = w + o * 4608 + t * 18;
#pragma unroll
    for (int k = 0; k < 9; k++) {
      float2 v2 = *(const float2*)(wp_ + 2 * k);
      wreg[2 * k] = v2.x;
      wreg[2 * k + 1] = v2.y;
    }
    // W' store: row tap*512+o, element 2t..2t+1 (batch-independent, 9 x 1KB/block)
    {
      ushort* base = Wp + (size_t)o * 512 + 2 * t;
#pragma unroll
      for (int tap = 0; tap < 9; tap++) {
        ushort2 val = make_ushort2(f2bf(GAIN * wreg[tap]), f2bf(GAIN * wreg[9 + tap]));
        *(ushort2*)(base + (size_t)tap * 262144) = val;
      }
    }
    float q0 = 0.f, q1 = 0.f;
#pragma unroll
    for (int k = 0; k < 9; k++) {
      q0 += wreg[k] * wreg[k];
      q1 += wreg[9 + k] * wreg[9 + k];
    }
    __syncthreads();  // ss ready
    float pb[8];
#pragma unroll
    for (int b = 0; b < 8; b++) {
      float s0 = sm.wp.ss[b * 512 + 2 * t] + 1.0f;
      float s1 = sm.wp.ss[b * 512 + 2 * t + 1] + 1.0f;
      pb[b] = s0 * s0 * q0 + s1 * s1 * q1;
    }
#pragma unroll
    for (int b = 0; b < 8; b++)
#pragma unroll
      for (int off = 32; off > 0; off >>= 1) pb[b] += __shfl_down(pb[b], off, 64);
    const int wid = t >> 6, lane = t & 63;
    if (lane == 0) {
#pragma unroll
      for (int b = 0; b < 8; b++) sm.wp.wred[wid][b] = pb[b];
    }
    __syncthreads();
    if (t < 8)
      dcg[t * 512 + o] = rsqrtf((sm.wp.wred[0][t] + sm.wp.wred[1][t] + sm.wp.wred[2][t] +
                                 sm.wp.wred[3][t]) * (GAIN * GAIN) + 1e-8f);
  } else {
    // ---- styled x transpose: tile 32 i x 256 hw; xs = (s+1)*x ----
    const int idx = blockIdx.x - 512;
    const int hw0 = (idx & 3) * 256, i0 = ((idx >> 2) & 15) * 32, b = idx >> 6;
    const float* xb = x + b * (512 * 1024);
    if (t < 32) sst[t] = styles[b * 512 + i0 + t] + 1.0f;
#pragma unroll
    for (int p = 0; p < 8; p++) {
      const int r = p * 4 + (t >> 6);
      const int c4 = (t & 63) * 4;
      float4 v = *(const float4*)&xb[(i0 + r) * 1024 + hw0 + c4];
      sm.tl[r][c4] = v.x; sm.tl[r][c4 + 1] = v.y; sm.tl[r][c4 + 2] = v.z; sm.tl[r][c4 + 3] = v.w;
    }
    __syncthreads();
    ushort* xtb = xs + b * (1024 * 512);
#pragma unroll
    for (int p = 0; p < 8; p++) {
      const int hw = p * 32 + (t >> 3);
      const int i4 = (t & 7) * 4;
      ushort4 v = make_ushort4(f2bf(sm.tl[i4][hw] * sst[i4]),
                               f2bf(sm.tl[i4 + 1][hw] * sst[i4 + 1]),
                               f2bf(sm.tl[i4 + 2][hw] * sst[i4 + 2]),
                               f2bf(sm.tl[i4 + 3][hw] * sst[i4 + 3]));
      *(ushort4*)&xtb[(hw0 + hw) * 512 + i0 + i4] = v;
    }
  }
}

// ---------------- K2: 8 x GEMM (M=4608,N=1024,K=512), C[b] = (W' @ XS[b]^T) * dc -------
// R2 structure (best measured): 192x256 tile, BK=64, 8 waves (2M x 4N), wave 96x64.
// LDS 112 KiB = 2dbuf x { A[192][64] 24KB , B[256][64] 32KB }, rows 128 B, slot^=(row&7)
// swizzle (linear gl_load_lds dest + inverse-swizzled global source + swizzled ds_read).
// A is batch-SHARED (4.7 MB, L2/L3-resident across all 8 batches).
// Per K-tile, 4 phases (reads before barrier, MFMA after; kk-outer = indep chains):
//   P1: read A mi0-2 (6) + B ni0-1 (4) | BAR | MFMA mi0-2 x ni0-1 (12) | BAR
//   P2: read B ni2-3 (4)               | BAR | MFMA mi0-2 x ni2-3 (12) | BAR
//   P3: read A mi3-5 (6), STAGE_B(t+2) | BAR | MFMA mi3-5 x ni0-1 (12) | BAR
//   P4: STAGE_A(t+2)                         | MFMA mi3-5 x ni2-3 (12) | vmcnt(7) | BAR
// Epilogue: per-row dc[b][(m0+row)&511] multiply before f2bf, LDS-staged 16B stores.
__global__ __launch_bounds__(512, 2) void k_gemm(const ushort* __restrict__ A,
                                                 const ushort* __restrict__ Bt,
                                                 const float* __restrict__ dcoef,
                                                 ushort* __restrict__ C) {
  __shared__ __attribute__((aligned(128))) char smem[114688];
  __shared__ float dcl[192];
  const int id = blockIdx.x;
  const int batch = id & 7;        // XCD affinity: XS slab (1 MB) stays L2-resident
  const int rem = id >> 3;         // 0..95: mt-major
  const int mt = rem >> 2, nt = rem & 3;
  const int m0 = mt * 192, n0 = nt * 256;
  const ushort* Ag = A;                                   // SHARED across batches
  const ushort* Bg = Bt + (size_t)batch * (1024 * 512);
  ushort* Cg = C + (size_t)batch * (4608 * 1024);

  const int tid = threadIdx.x;
  const int w = tid >> 6, lane = tid & 63;
  const int wm = w >> 2, wn = w & 3;            // wave tile: rows wm*96, cols wn*64
  const int lq = lane >> 4, l15 = lane & 15, l7 = lane & 7;
  const int rlow = lane >> 3;                   // staging row low bits (0..7)
  const int ssw = (lane & 7) ^ rlow;            // inverse-swizzled source slot

  if (tid < 192) dcl[tid] = dcoef[batch * 512 + ((m0 + tid) & 511)];

  const char* pA = (const char*)Ag + (size_t)(m0 + w * 24 + rlow) * 1024 + ssw * 16;
  const char* pB = (const char*)Bg + (size_t)(n0 + w * 32 + rlow) * 1024 + ssw * 16;
  char* dA = smem + w * 3072;                   // wave's 3 A chunks (+buf*24576)
  char* dB = smem + 49152 + w * 4096;           // wave's 4 B chunks (+buf*32768)

#define GLL(srcp, dstp)                                                                     \
  __builtin_amdgcn_global_load_lds((const __attribute__((address_space(1))) void*)(srcp),   \
                                   (__attribute__((address_space(3))) void*)(dstp), 16, 0, 0)
#define STAGE_A(buf, kt)                                            \
  do {                                                              \
    GLL(pA + 0 * 8192 + (kt) * 128, dA + (buf) * 24576 + 0 * 1024); \
    GLL(pA + 1 * 8192 + (kt) * 128, dA + (buf) * 24576 + 1 * 1024); \
    GLL(pA + 2 * 8192 + (kt) * 128, dA + (buf) * 24576 + 2 * 1024); \
  } while (0)
#define STAGE_B(buf, kt)                                            \
  do {                                                              \
    GLL(pB + 0 * 8192 + (kt) * 128, dB + (buf) * 32768 + 0 * 1024); \
    GLL(pB + 1 * 8192 + (kt) * 128, dB + (buf) * 32768 + 1 * 1024); \
    GLL(pB + 2 * 8192 + (kt) * 128, dB + (buf) * 32768 + 2 * 1024); \
    GLL(pB + 3 * 8192 + (kt) * 128, dB + (buf) * 32768 + 3 * 1024); \
  } while (0)
#define CF asm volatile("" ::: "memory")
#define BAR()                          \
  do {                                 \
    CF;                                \
    __builtin_amdgcn_s_barrier();      \
    CF;                                \
  } while (0)

  // ds_read bases: row = frag row base + l15; swizzled slot = (kk*4+lq) ^ (row&7)
  const char* Ard = smem + (wm * 96 + l15) * 128;
  const char* Brd = smem + 49152 + (wn * 64 + l15) * 128;
  const int s0o = (lq ^ l7) * 16;        // kk=0 slot (swizzled), bytes
  const int s1o = ((4 + lq) ^ l7) * 16;  // kk=1 slot

  f32x4 acc[6][4];
  const f32x4 z4 = {0.f, 0.f, 0.f, 0.f};
#pragma unroll
  for (int i = 0; i < 6; ++i)
#pragma unroll
    for (int n = 0; n < 4; ++n) acc[i][n] = z4;

  // Prologue: stage tiles 0 (buf0) and 1 (buf1); keep tile1's 7 loads in flight.
  STAGE_A(0, 0); STAGE_B(0, 0);
  STAGE_A(1, 1); STAGE_B(1, 1);
  asm volatile("s_waitcnt vmcnt(7)" ::: "memory");
  BAR();

#pragma unroll
  for (int t = 0; t < 8; ++t) {
    const int buf = t & 1;
    const char* Ab = Ard + buf * 24576;
    const char* Bb = Brd + buf * 32768;
    bf16x8 a[3][2], a2[3][2], b[4][2];
    // ---- P1: read A mi0-2 + B ni0-1; MFMA mi0-2 x ni0-1 ----
#pragma unroll
    for (int i = 0; i < 3; ++i) {
      a[i][0] = *(const bf16x8*)(Ab + i * 2048 + s0o);
      a[i][1] = *(const bf16x8*)(Ab + i * 2048 + s1o);
    }
#pragma unroll
    for (int n = 0; n < 2; ++n) {
      b[n][0] = *(const bf16x8*)(Bb + n * 2048 + s0o);
      b[n][1] = *(const bf16x8*)(Bb + n * 2048 + s1o);
    }
    BAR();
    __builtin_amdgcn_s_setprio(1);
#pragma unroll
    for (int kk = 0; kk < 2; ++kk)
#pragma unroll
      for (int n = 0; n < 2; ++n)
#pragma unroll
        for (int i = 0; i < 3; ++i)
          acc[i][n] = __builtin_amdgcn_mfma_f32_16x16x32_bf16(a[i][kk], b[n][kk], acc[i][n], 0, 0, 0);
    __builtin_amdgcn_s_setprio(0);
    BAR();
    // ---- P2: read B ni2-3; MFMA mi0-2 x ni2-3 ----
#pragma unroll
    for (int n = 2; n < 4; ++n) {
      b[n][0] = *(const bf16x8*)(Bb + n * 2048 + s0o);
      b[n][1] = *(const bf16x8*)(Bb + n * 2048 + s1o);
    }
    BAR();
    __builtin_amdgcn_s_setprio(1);
#pragma unroll
    for (int kk = 0; kk < 2; ++kk)
#pragma unroll
      for (int n = 2; n < 4; ++n)
#pragma unroll
        for (int i = 0; i < 3; ++i)
          acc[i][n] = __builtin_amdgcn_mfma_f32_16x16x32_bf16(a[i][kk], b[n][kk], acc[i][n], 0, 0, 0);
    __builtin_amdgcn_s_setprio(0);
    BAR();
    // ---- P3: read A mi3-5 + stage B(t+2); MFMA mi3-5 x ni0-1 ----
#pragma unroll
    for (int i = 0; i < 3; ++i) {
      a2[i][0] = *(const bf16x8*)(Ab + (3 + i) * 2048 + s0o);
      a2[i][1] = *(const bf16x8*)(Ab + (3 + i) * 2048 + s1o);
    }
    if (t < 6) STAGE_B(buf, t + 2);
    BAR();
    __builtin_amdgcn_s_setprio(1);
#pragma unroll
    for (int kk = 0; kk < 2; ++kk)
#pragma unroll
      for (int n = 0; n < 2; ++n)
#pragma unroll
        for (int i = 0; i < 3; ++i)
          acc[3 + i][n] = __builtin_amdgcn_mfma_f32_16x16x32_bf16(a2[i][kk], b[n][kk], acc[3 + i][n], 0, 0, 0);
    __builtin_amdgcn_s_setprio(0);
    BAR();
    // ---- P4: stage A(t+2); MFMA mi3-5 x ni2-3 (all operands in regs); vmcnt gate ----
    if (t < 6) STAGE_A(buf, t + 2);
    __builtin_amdgcn_s_setprio(1);
#pragma unroll
    for (int kk = 0; kk < 2; ++kk)
#pragma unroll
      for (int n = 2; n < 4; ++n)
#pragma unroll
        for (int i = 0; i < 3; ++i)
          acc[3 + i][n] = __builtin_amdgcn_mfma_f32_16x16x32_bf16(a2[i][kk], b[n][kk], acc[3 + i][n], 0, 0, 0);
    __builtin_amdgcn_s_setprio(0);
    if (t < 6) {
      asm volatile("s_waitcnt vmcnt(7)" ::: "memory");  // t+1 landed; t+2's 7 in flight
    } else if (t == 6) {
      asm volatile("s_waitcnt vmcnt(0)" ::: "memory");  // drain: tile 7 landed
    }
    BAR();
  }

  // Epilogue: dc-scale, stage bf16 C in LDS (96 x 264-ushort stride), 16B stores.
  ushort* cs = (ushort*)smem;
#pragma unroll
  for (int p = 0; p < 2; ++p) {
    if (p) BAR();
    if (wm == p) {
#pragma unroll
      for (int mi = 0; mi < 6; ++mi)
#pragma unroll
        for (int n = 0; n < 4; ++n) {
          const int row = mi * 16 + lq * 4;
          const int col = wn * 64 + n * 16 + l15;
          const f32x4 v = acc[mi][n];
#pragma unroll
          for (int r = 0; r < 4; ++r)
            cs[(row + r) * 264 + col] = f2bf(v[r] * dcl[p * 96 + row + r]);
        }
    }
    BAR();
#pragma unroll
    for (int j = 0; j < 6; ++j) {
      const int idx = j * 512 + tid;
      const int row = idx >> 5, c = idx & 31;
      *(uint4*)(Cg + (size_t)(m0 + p * 96 + row) * 1024 + n0 + c * 8) =
          *(const uint4*)(cs + row * 264 + c * 8);
    }
  }
#undef GLL
#undef STAGE_A
#undef STAGE_B
#undef CF
#undef BAR
}

// ---------------- K3: parity scatter + separable FIR, one (b,o) per block, 512 thr ------
// Stage1: V[kw][u][w] = sum_{kh,d} F*C[kh*3+kw][h][w], V row stride 36 (bank spread)
// Stage2: out[u][v] = (1/16) sum_{kw,d} F*V[kw][u][(v+t0+2d-1-kw)/2]
__global__ __launch_bounds__(512) void k_fir(const ushort* __restrict__ C,
                                             float* __restrict__ out) {
  const int bo = blockIdx.x;
  const int b = bo >> 9, o = bo & 511;
  __shared__ __attribute__((aligned(16))) ushort Ct[9 * 1024];
  __shared__ float V[3 * 64 * 36];
  const ushort* Cb = C + ((size_t)(b * 9) * 512 + o) * 1024;
  for (int c = threadIdx.x; c < 1152; c += 512) {
    const int tap = c >> 7, off = (c & 127) * 8;
    *(uint4*)&Ct[tap * 1024 + off] = *(const uint4*)&Cb[(size_t)tap * 524288 + off];
  }
  __syncthreads();
#pragma unroll
  for (int j = 0; j < 3; j++) {
    const int gidx = threadIdx.x + j * 512;  // (kw, u, w0/4)
    const int kw = gidx >> 9;
    const int rem = gidx & 511;
    const int u = rem >> 3;
    const int w0 = (rem & 7) * 4;
    float a0 = 0.f, a1 = 0.f, a2 = 0.f, a3 = 0.f;
#pragma unroll
    for (int kh = 0; kh < 3; kh++) {
      const int s0 = (kh + 1 + u) & 1;
#pragma unroll
      for (int d = 0; d < 2; d++) {
        const int h = (u + s0 + 2 * d - 1 - kh) >> 1;
        const bool ok = (h >= 0) & (h < 32);
        const float cf = ok ? ((s0 == d) ? 1.f : 3.f) : 0.f;
        const int hh = ok ? h : 0;
        const uint2 cv = *(const uint2*)&Ct[kh * 3072 + kw * 1024 + hh * 32 + w0];
        a0 += cf * bf2f((ushort)(cv.x & 0xffff));
        a1 += cf * bf2f((ushort)(cv.x >> 16));
        a2 += cf * bf2f((ushort)(cv.y & 0xffff));
        a3 += cf * bf2f((ushort)(cv.y >> 16));
      }
    }
    *(float4*)&V[kw * 2304 + u * 36 + w0] = make_float4(a0, a1, a2, a3);
  }
  __syncthreads();
  const size_t ob = (size_t)bo * 4096;
#pragma unroll
  for (int j = 0; j < 2; j++) {
    const int px4 = threadIdx.x + j * 512;
    const int u = px4 >> 4;
    const int v0 = (px4 & 15) * 4;
    float r[4] = {0.f, 0.f, 0.f, 0.f};
#pragma unroll
    for (int q = 0; q < 4; q++) {
      const int v = v0 + q;
#pragma unroll
      for (int kw = 0; kw < 3; kw++) {
        const int t0 = (kw + 1 + v) & 1;
#pragma unroll
        for (int d = 0; d < 2; d++) {
          const int wx = (v + t0 + 2 * d - 1 - kw) >> 1;
          const bool ok = (wx >= 0) & (wx < 32);
          const float cf = ok ? ((t0 == d) ? 1.f : 3.f) : 0.f;
          const int ww = ok ? wx : 0;
          r[q] += cf * V[kw * 2304 + u * 36 + ww];
        }
      }
      r[q] *= 0.0625f;
    }
    *(float4*)&out[ob + u * 64 + v0] = make_float4(r[0], r[1], r[2], r[3]);
  }
}

extern "C" void kernel_launch(void* const* d_in, const int* in_sizes, int n_in,
                              void* d_out, int out_size, void* d_ws, size_t ws_size,
                              hipStream_t stream) {
  (void)in_sizes; (void)n_in; (void)out_size; (void)ws_size;
  const float* x = (const float*)d_in[0];       // [8,512,32,32] fp32
  const float* styles = (const float*)d_in[1];  // [8,512] fp32
  const float* w = (const float*)d_in[2];       // [512,512,3,3] fp32
  float* out = (float*)d_out;                   // [8,512,64,64] fp32
  char* ws = (char*)d_ws;
  ushort* Wp = (ushort*)ws;                      // 4,718,592 B  (shared gain*w bf16)
  float* dcg = (float*)(ws + 4718592);           // 16,384 B     (dc[b][o])
  ushort* XS = (ushort*)(ws + 4734976);          // 8,388,608 B  (styled x^T bf16)
  ushort* C = (ushort*)(ws + 13123584);          // 75,497,472 B

  k_prep<<<1024, 256, 0, stream>>>(w, styles, x, Wp, dcg, XS);
  k_gemm<<<768, 512, 0, stream>>>(Wp, XS, dcg, C);
  k_fir<<<4096, 512, 0, stream>>>(C, out);
}

// Round 7
// 156.382 us; speedup vs baseline: 1.0201x; 1.0201x over previous
//
#include <hip/hip_runtime.h>
#include <stdint.h>

// ModulatedConv (StyleGAN2 up-conv): B=8, Cin=Cout=512, K=3, 32x32 -> 64x64, fp32 I/O.
// Factorized pipeline (style folded into X, demod into GEMM epilogue):
//   C[b,tap,o,hw] = dc[b,o] * sum_i (gain*w)[tap*512+o,i] * ((s[b,i]+1)*x[b,i,hw])
//   K1 k_prep:  blocks 0..511  = dc[b][o] (16 KB) + SHARED W' = gain*w bf16 [4608][512]
//               (4.7 MB, batch-independent); blocks 512..1023 = XS[b][hw][i] bf16
//               (style-premultiplied transpose, 8.39 MB)
//   K2 k_gemm:  per batch GEMM M=4608,N=1024,K=512 (R2 4-phase counted-vmcnt structure,
//               frozen at ~57us), dc multiply in epilogue.
//   K3 k_fir:   REWRITTEN stage2: compile-time coef/index tables, 10 imm-offset
//               ds_read_b32 + 24 FMA per quad (was 24 clamped reads + runtime selects);
//               V stride 37 (odd -> ~2-way banks, free) with guard-zero slots.

#define DI __device__ __forceinline__

typedef __bf16 bf16x8 __attribute__((ext_vector_type(8)));
typedef float f32x4 __attribute__((ext_vector_type(4)));

DI float bf2f(ushort u) { union { uint32_t i; float f; } v; v.i = ((uint32_t)u) << 16; return v.f; }
DI ushort f2bf(float f) {
  union { float f; uint32_t i; } v; v.f = f;
  uint32_t x = v.i;
  return (ushort)((x + 0x7FFFu + ((x >> 16) & 1u)) >> 16);  // RNE
}

#define GAIN (1.0f / 1536.0f)  // 1/sqrt(512*512*9)

// ---------------- K1: dcoef + shared-W' prep (0..511) | styled x-transpose (512..1023) --
__global__ __launch_bounds__(256) void k_prep(const float* __restrict__ w,
                                              const float* __restrict__ styles,
                                              const float* __restrict__ x,
                                              ushort* __restrict__ Wp,
                                              float* __restrict__ dcg,
                                              ushort* __restrict__ xs) {
  __shared__ union {
    struct { float ss[4096]; float wred[4][8]; } wp;
    float tl[32][257];
  } sm;
  __shared__ float sst[32];
  const int t = threadIdx.x;
  if (blockIdx.x < 512) {
    // ---- block per o. Thread t owns i = 2t, 2t+1. ----
    const int o = blockIdx.x;
#pragma unroll
    for (int j = 0; j < 4; j++) {
      const int idx = (t + j * 256) * 4;
      *(float4*)&sm.wp.ss[idx] = *(const float4*)&styles[idx];
    }
    float wreg[18];
    const float* wp_ = w + o * 4608 + t * 18;
#pragma unroll
    for (int k = 0; k < 9; k++) {
      float2 v2 = *(const float2*)(wp_ + 2 * k);
      wreg[2 * k] = v2.x;
      wreg[2 * k + 1] = v2.y;
    }
    // W' store: row tap*512+o, element 2t..2t+1 (batch-independent, 9 x 1KB/block)
    {
      ushort* base = Wp + (size_t)o * 512 + 2 * t;
#pragma unroll
      for (int tap = 0; tap < 9; tap++) {
        ushort2 val = make_ushort2(f2bf(GAIN * wreg[tap]), f2bf(GAIN * wreg[9 + tap]));
        *(ushort2*)(base + (size_t)tap * 262144) = val;
      }
    }
    float q0 = 0.f, q1 = 0.f;
#pragma unroll
    for (int k = 0; k < 9; k++) {
      q0 += wreg[k] * wreg[k];
      q1 += wreg[9 + k] * wreg[9 + k];
    }
    __syncthreads();  // ss ready
    float pb[8];
#pragma unroll
    for (int b = 0; b < 8; b++) {
      float s0 = sm.wp.ss[b * 512 + 2 * t] + 1.0f;
      float s1 = sm.wp.ss[b * 512 + 2 * t + 1] + 1.0f;
      pb[b] = s0 * s0 * q0 + s1 * s1 * q1;
    }
#pragma unroll
    for (int b = 0; b < 8; b++)
#pragma unroll
      for (int off = 32; off > 0; off >>= 1) pb[b] += __shfl_down(pb[b], off, 64);
    const int wid = t >> 6, lane = t & 63;
    if (lane == 0) {
#pragma unroll
      for (int b = 0; b < 8; b++) sm.wp.wred[wid][b] = pb[b];
    }
    __syncthreads();
    if (t < 8)
      dcg[t * 512 + o] = rsqrtf((sm.wp.wred[0][t] + sm.wp.wred[1][t] + sm.wp.wred[2][t] +
                                 sm.wp.wred[3][t]) * (GAIN * GAIN) + 1e-8f);
  } else {
    // ---- styled x transpose: tile 32 i x 256 hw; xs = (s+1)*x ----
    const int idx = blockIdx.x - 512;
    const int hw0 = (idx & 3) * 256, i0 = ((idx >> 2) & 15) * 32, b = idx >> 6;
    const float* xb = x + b * (512 * 1024);
    if (t < 32) sst[t] = styles[b * 512 + i0 + t] + 1.0f;
#pragma unroll
    for (int p = 0; p < 8; p++) {
      const int r = p * 4 + (t >> 6);
      const int c4 = (t & 63) * 4;
      float4 v = *(const float4*)&xb[(i0 + r) * 1024 + hw0 + c4];
      sm.tl[r][c4] = v.x; sm.tl[r][c4 + 1] = v.y; sm.tl[r][c4 + 2] = v.z; sm.tl[r][c4 + 3] = v.w;
    }
    __syncthreads();
    ushort* xtb = xs + b * (1024 * 512);
#pragma unroll
    for (int p = 0; p < 8; p++) {
      const int hw = p * 32 + (t >> 3);
      const int i4 = (t & 7) * 4;
      ushort4 v = make_ushort4(f2bf(sm.tl[i4][hw] * sst[i4]),
                               f2bf(sm.tl[i4 + 1][hw] * sst[i4 + 1]),
                               f2bf(sm.tl[i4 + 2][hw] * sst[i4 + 2]),
                               f2bf(sm.tl[i4 + 3][hw] * sst[i4 + 3]));
      *(ushort4*)&xtb[(hw0 + hw) * 512 + i0 + i4] = v;
    }
  }
}

// ---------------- K2: 8 x GEMM (M=4608,N=1024,K=512), C[b] = (W' @ XS[b]^T) * dc -------
// Frozen R2 structure: 192x256 tile, BK=64, 8 waves (2M x 4N), wave 96x64.
// LDS 112 KiB = 2dbuf x { A[192][64] 24KB , B[256][64] 32KB }, rows 128 B, slot^=(row&7)
// swizzle. 4 phases/K-tile, counted vmcnt(7), raw barriers, setprio, kk-outer MFMA.
__global__ __launch_bounds__(512, 2) void k_gemm(const ushort* __restrict__ A,
                                                 const ushort* __restrict__ Bt,
                                                 const float* __restrict__ dcoef,
                                                 ushort* __restrict__ C) {
  __shared__ __attribute__((aligned(128))) char smem[114688];
  __shared__ float dcl[192];
  const int id = blockIdx.x;
  const int batch = id & 7;        // XCD affinity: XS slab (1 MB) stays L2-resident
  const int rem = id >> 3;         // 0..95: mt-major
  const int mt = rem >> 2, nt = rem & 3;
  const int m0 = mt * 192, n0 = nt * 256;
  const ushort* Ag = A;                                   // SHARED across batches
  const ushort* Bg = Bt + (size_t)batch * (1024 * 512);
  ushort* Cg = C + (size_t)batch * (4608 * 1024);

  const int tid = threadIdx.x;
  const int w = tid >> 6, lane = tid & 63;
  const int wm = w >> 2, wn = w & 3;            // wave tile: rows wm*96, cols wn*64
  const int lq = lane >> 4, l15 = lane & 15, l7 = lane & 7;
  const int rlow = lane >> 3;                   // staging row low bits (0..7)
  const int ssw = (lane & 7) ^ rlow;            // inverse-swizzled source slot

  if (tid < 192) dcl[tid] = dcoef[batch * 512 + ((m0 + tid) & 511)];

  const char* pA = (const char*)Ag + (size_t)(m0 + w * 24 + rlow) * 1024 + ssw * 16;
  const char* pB = (const char*)Bg + (size_t)(n0 + w * 32 + rlow) * 1024 + ssw * 16;
  char* dA = smem + w * 3072;                   // wave's 3 A chunks (+buf*24576)
  char* dB = smem + 49152 + w * 4096;           // wave's 4 B chunks (+buf*32768)

#define GLL(srcp, dstp)                                                                     \
  __builtin_amdgcn_global_load_lds((const __attribute__((address_space(1))) void*)(srcp),   \
                                   (__attribute__((address_space(3))) void*)(dstp), 16, 0, 0)
#define STAGE_A(buf, kt)                                            \
  do {                                                              \
    GLL(pA + 0 * 8192 + (kt) * 128, dA + (buf) * 24576 + 0 * 1024); \
    GLL(pA + 1 * 8192 + (kt) * 128, dA + (buf) * 24576 + 1 * 1024); \
    GLL(pA + 2 * 8192 + (kt) * 128, dA + (buf) * 24576 + 2 * 1024); \
  } while (0)
#define STAGE_B(buf, kt)                                            \
  do {                                                              \
    GLL(pB + 0 * 8192 + (kt) * 128, dB + (buf) * 32768 + 0 * 1024); \
    GLL(pB + 1 * 8192 + (kt) * 128, dB + (buf) * 32768 + 1 * 1024); \
    GLL(pB + 2 * 8192 + (kt) * 128, dB + (buf) * 32768 + 2 * 1024); \
    GLL(pB + 3 * 8192 + (kt) * 128, dB + (buf) * 32768 + 3 * 1024); \
  } while (0)
#define CF asm volatile("" ::: "memory")
#define BAR()                          \
  do {                                 \
    CF;                                \
    __builtin_amdgcn_s_barrier();      \
    CF;                                \
  } while (0)

  // ds_read bases: row = frag row base + l15; swizzled slot = (kk*4+lq) ^ (row&7)
  const char* Ard = smem + (wm * 96 + l15) * 128;
  const char* Brd = smem + 49152 + (wn * 64 + l15) * 128;
  const int s0o = (lq ^ l7) * 16;        // kk=0 slot (swizzled), bytes
  const int s1o = ((4 + lq) ^ l7) * 16;  // kk=1 slot

  f32x4 acc[6][4];
  const f32x4 z4 = {0.f, 0.f, 0.f, 0.f};
#pragma unroll
  for (int i = 0; i < 6; ++i)
#pragma unroll
    for (int n = 0; n < 4; ++n) acc[i][n] = z4;

  // Prologue: stage tiles 0 (buf0) and 1 (buf1); keep tile1's 7 loads in flight.
  STAGE_A(0, 0); STAGE_B(0, 0);
  STAGE_A(1, 1); STAGE_B(1, 1);
  asm volatile("s_waitcnt vmcnt(7)" ::: "memory");
  BAR();

#pragma unroll
  for (int t = 0; t < 8; ++t) {
    const int buf = t & 1;
    const char* Ab = Ard + buf * 24576;
    const char* Bb = Brd + buf * 32768;
    bf16x8 a[3][2], a2[3][2], b[4][2];
    // ---- P1: read A mi0-2 + B ni0-1; MFMA mi0-2 x ni0-1 ----
#pragma unroll
    for (int i = 0; i < 3; ++i) {
      a[i][0] = *(const bf16x8*)(Ab + i * 2048 + s0o);
      a[i][1] = *(const bf16x8*)(Ab + i * 2048 + s1o);
    }
#pragma unroll
    for (int n = 0; n < 2; ++n) {
      b[n][0] = *(const bf16x8*)(Bb + n * 2048 + s0o);
      b[n][1] = *(const bf16x8*)(Bb + n * 2048 + s1o);
    }
    BAR();
    __builtin_amdgcn_s_setprio(1);
#pragma unroll
    for (int kk = 0; kk < 2; ++kk)
#pragma unroll
      for (int n = 0; n < 2; ++n)
#pragma unroll
        for (int i = 0; i < 3; ++i)
          acc[i][n] = __builtin_amdgcn_mfma_f32_16x16x32_bf16(a[i][kk], b[n][kk], acc[i][n], 0, 0, 0);
    __builtin_amdgcn_s_setprio(0);
    BAR();
    // ---- P2: read B ni2-3; MFMA mi0-2 x ni2-3 ----
#pragma unroll
    for (int n = 2; n < 4; ++n) {
      b[n][0] = *(const bf16x8*)(Bb + n * 2048 + s0o);
      b[n][1] = *(const bf16x8*)(Bb + n * 2048 + s1o);
    }
    BAR();
    __builtin_amdgcn_s_setprio(1);
#pragma unroll
    for (int kk = 0; kk < 2; ++kk)
#pragma unroll
      for (int n = 2; n < 4; ++n)
#pragma unroll
        for (int i = 0; i < 3; ++i)
          acc[i][n] = __builtin_amdgcn_mfma_f32_16x16x32_bf16(a[i][kk], b[n][kk], acc[i][n], 0, 0, 0);
    __builtin_amdgcn_s_setprio(0);
    BAR();
    // ---- P3: read A mi3-5 + stage B(t+2); MFMA mi3-5 x ni0-1 ----
#pragma unroll
    for (int i = 0; i < 3; ++i) {
      a2[i][0] = *(const bf16x8*)(Ab + (3 + i) * 2048 + s0o);
      a2[i][1] = *(const bf16x8*)(Ab + (3 + i) * 2048 + s1o);
    }
    if (t < 6) STAGE_B(buf, t + 2);
    BAR();
    __builtin_amdgcn_s_setprio(1);
#pragma unroll
    for (int kk = 0; kk < 2; ++kk)
#pragma unroll
      for (int n = 0; n < 2; ++n)
#pragma unroll
        for (int i = 0; i < 3; ++i)
          acc[3 + i][n] = __builtin_amdgcn_mfma_f32_16x16x32_bf16(a2[i][kk], b[n][kk], acc[3 + i][n], 0, 0, 0);
    __builtin_amdgcn_s_setprio(0);
    BAR();
    // ---- P4: stage A(t+2); MFMA mi3-5 x ni2-3 (all operands in regs); vmcnt gate ----
    if (t < 6) STAGE_A(buf, t + 2);
    __builtin_amdgcn_s_setprio(1);
#pragma unroll
    for (int kk = 0; kk < 2; ++kk)
#pragma unroll
      for (int n = 2; n < 4; ++n)
#pragma unroll
        for (int i = 0; i < 3; ++i)
          acc[3 + i][n] = __builtin_amdgcn_mfma_f32_16x16x32_bf16(a2[i][kk], b[n][kk], acc[3 + i][n], 0, 0, 0);
    __builtin_amdgcn_s_setprio(0);
    if (t < 6) {
      asm volatile("s_waitcnt vmcnt(7)" ::: "memory");  // t+1 landed; t+2's 7 in flight
    } else if (t == 6) {
      asm volatile("s_waitcnt vmcnt(0)" ::: "memory");  // drain: tile 7 landed
    }
    BAR();
  }

  // Epilogue: dc-scale, stage bf16 C in LDS (96 x 264-ushort stride), 16B stores.
  ushort* cs = (ushort*)smem;
#pragma unroll
  for (int p = 0; p < 2; ++p) {
    if (p) BAR();
    if (wm == p) {
#pragma unroll
      for (int mi = 0; mi < 6; ++mi)
#pragma unroll
        for (int n = 0; n < 4; ++n) {
          const int row = mi * 16 + lq * 4;
          const int col = wn * 64 + n * 16 + l15;
          const f32x4 v = acc[mi][n];
#pragma unroll
          for (int r = 0; r < 4; ++r)
            cs[(row + r) * 264 + col] = f2bf(v[r] * dcl[p * 96 + row + r]);
        }
    }
    BAR();
#pragma unroll
    for (int j = 0; j < 6; ++j) {
      const int idx = j * 512 + tid;
      const int row = idx >> 5, c = idx & 31;
      *(uint4*)(Cg + (size_t)(m0 + p * 96 + row) * 1024 + n0 + c * 8) =
          *(const uint4*)(cs + row * 264 + c * 8);
    }
  }
#undef GLL
#undef STAGE_A
#undef STAGE_B
#undef CF
#undef BAR
}

// ---------------- K3: parity scatter + separable FIR, one (b,o) per block, 512 thr ------
// Stage1 (unchanged math): V[kw][u][w] = sum_{kh,d} cf*C[kh*3+kw][h][w]; V stride 37
// (odd -> ~2-way banks) with guard zeros at slot 32 (w+2 overflow) and slot 36 (w-1 of
// the next row) so stage2 needs NO clamps/selects.
// Stage2 (rewritten): per (u, v-quad) the read window is V[kw][u][w-1..w+2], w=v0/2.
// All indices/coefs compile-time:
//   q0 = 3A1+A2 + B0+3B1 + 3D0+D1     q1 = A1+3A2 + 3B1+B2 + D0+3D1
//   q2 = 3A2+A3 + B1+3B2 + 3D1+D2     q3 = A2+3A3 + 3B2+B3 + D1+3D2
// (A=kw0 window offset +1..+3; B=kw1, D=kw2 offset 0..3; verified vs original at
//  v=0, v=10, v=63 including boundary-zero cases). 10 imm-offset ds_read_b32 + 24 FMA.
__global__ __launch_bounds__(512) void k_fir(const ushort* __restrict__ C,
                                             float* __restrict__ out) {
  const int bo = blockIdx.x;
  const int b = bo >> 9, o = bo & 511;
  __shared__ __attribute__((aligned(16))) ushort Ct[9 * 1024];
  __shared__ __attribute__((aligned(16))) float Varr[3 * 64 * 37 + 1];
  float* V = Varr + 1;  // V[kw*2368 + u*37 + w], w addressable from -1
  const ushort* Cb = C + ((size_t)(b * 9) * 512 + o) * 1024;
  for (int c = threadIdx.x; c < 1152; c += 512) {
    const int tap = c >> 7, off = (c & 127) * 8;
    *(uint4*)&Ct[tap * 1024 + off] = *(const uint4*)&Cb[(size_t)tap * 524288 + off];
  }
  if (threadIdx.x < 192) {
    const int gbase = (threadIdx.x >> 6) * 2368 + (threadIdx.x & 63) * 37;
    V[gbase + 32] = 0.f;  // w+2 overflow guard (read when w=30)
    V[gbase + 36] = 0.f;  // serves as w-1 guard of the FOLLOWING row
  }
  if (threadIdx.x == 192) V[-1] = 0.f;  // w-1 guard of (kw0, u0)
  __syncthreads();
#pragma unroll
  for (int j = 0; j < 3; j++) {
    const int gidx = threadIdx.x + j * 512;  // (kw, u, w0/4)
    const int kw = gidx >> 9;
    const int rem = gidx & 511;
    const int u = rem >> 3;
    const int w0 = (rem & 7) * 4;
    float a0 = 0.f, a1 = 0.f, a2 = 0.f, a3 = 0.f;
#pragma unroll
    for (int kh = 0; kh < 3; kh++) {
      const int s0 = (kh + 1 + u) & 1;
#pragma unroll
      for (int d = 0; d < 2; d++) {
        const int h = (u + s0 + 2 * d - 1 - kh) >> 1;
        const bool ok = (h >= 0) & (h < 32);
        const float cf = ok ? ((s0 == d) ? 1.f : 3.f) : 0.f;
        const int hh = ok ? h : 0;
        const uint2 cv = *(const uint2*)&Ct[kh * 3072 + kw * 1024 + hh * 32 + w0];
        a0 += cf * bf2f((ushort)(cv.x & 0xffff));
        a1 += cf * bf2f((ushort)(cv.x >> 16));
        a2 += cf * bf2f((ushort)(cv.y & 0xffff));
        a3 += cf * bf2f((ushort)(cv.y >> 16));
      }
    }
    float* vp = &V[kw * 2368 + u * 37 + w0];
    vp[0] = a0; vp[1] = a1; vp[2] = a2; vp[3] = a3;
  }
  __syncthreads();
  const size_t ob = (size_t)bo * 4096;
#pragma unroll
  for (int j = 0; j < 2; j++) {
    const int px4 = threadIdx.x + j * 512;
    const int u = px4 >> 4;
    const int wl = (px4 & 15) * 2;  // w = v0/2, even; v0 = 2*wl
    const float* vp = &V[u * 37 + (wl - 1)];  // window base (w-1); guards make it safe
    const float A1 = vp[1], A2 = vp[2], A3 = vp[3];
    const float B0 = vp[2368], B1 = vp[2369], B2 = vp[2370], B3 = vp[2371];
    const float D0 = vp[4736], D1 = vp[4737], D2 = vp[4738];
    const float r0 = 3.f * A1 + A2 + B0 + 3.f * B1 + 3.f * D0 + D1;
    const float r1 = A1 + 3.f * A2 + 3.f * B1 + B2 + D0 + 3.f * D1;
    const float r2 = 3.f * A2 + A3 + B1 + 3.f * B2 + 3.f * D1 + D2;
    const float r3 = A2 + 3.f * A3 + 3.f * B2 + B3 + D1 + 3.f * D2;
    *(float4*)&out[ob + u * 64 + wl * 2] =
        make_float4(r0 * 0.0625f, r1 * 0.0625f, r2 * 0.0625f, r3 * 0.0625f);
  }
}

extern "C" void kernel_launch(void* const* d_in, const int* in_sizes, int n_in,
                              void* d_out, int out_size, void* d_ws, size_t ws_size,
                              hipStream_t stream) {
  (void)in_sizes; (void)n_in; (void)out_size; (void)ws_size;
  const float* x = (const float*)d_in[0];       // [8,512,32,32] fp32
  const float* styles = (const float*)d_in[1];  // [8,512] fp32
  const float* w = (const float*)d_in[2];       // [512,512,3,3] fp32
  float* out = (float*)d_out;                   // [8,512,64,64] fp32
  char* ws = (char*)d_ws;
  ushort* Wp = (ushort*)ws;                      // 4,718,592 B  (shared gain*w bf16)
  float* dcg = (float*)(ws + 4718592);           // 16,384 B     (dc[b][o])
  ushort* XS = (ushort*)(ws + 4734976);          // 8,388,608 B  (styled x^T bf16)
  ushort* C = (ushort*)(ws + 13123584);          // 75,497,472 B

  k_prep<<<1024, 256, 0, stream>>>(w, styles, x, Wp, dcg, XS);
  k_gemm<<<768, 512, 0, stream>>>(Wp, XS, dcg, C);
  k_fir<<<4096, 512, 0, stream>>>(C, out);
}